// Round 3
// baseline (441.203 us; speedup 1.0000x reference)
//
#include <hip/hip_runtime.h>

// MS-SSIM, 5 levels, 16x3x512x512 fp32, scalar fp32 out.
//
// R3: register-rolling column kernel. Thread = one image column; walks a row
// strip. Per input row: 11-float window from global (3 overlapping dwordx4,
// L1-hot halo), 5 h-channels in regs, scattered into 11 in-flight vertical
// accumulators with statically rotated Gaussian weights (row loop unrolled
// x11 -> all indices compile-time). One output row completes per step ->
// inline ssim/cs -> per-thread running sums -> one block reduce at the end.
// No LDS in the hot loop, no barriers, all 256 threads active.
// 2x2 avg-pool for the next level fused (waves 0-1 carry it as a side task).

#define NSLOT 32

typedef float v4  __attribute__((ext_vector_type(4)));
typedef float v2f __attribute__((ext_vector_type(2)));

__device__ __forceinline__ float frcp(float x) { return __builtin_amdgcn_rcpf(x); }

__global__ __launch_bounds__(256) void ssim_roll_kernel(
    const float* __restrict__ img1, const float* __restrict__ img2,
    float* __restrict__ ds1, float* __restrict__ ds2,
    int H, int logH, int SH, int do_ds, float* __restrict__ acc)
{
    const float GW[11] = {0.00102840f, 0.00759877f, 0.03600070f, 0.10936069f,
                          0.21300636f, 0.26601172f, 0.21300636f, 0.10936069f,
                          0.03600070f, 0.00759877f, 0.00102840f};
    const float C1 = 1e-4f, C2 = 9e-4f;

    const int tid  = threadIdx.x;
    const int gc   = blockIdx.x * 256 + tid;      // flattened (nc, col)
    const int nc   = gc >> logH;
    const int c    = gc & (H - 1);
    const int outW = H - 10;
    const int cb   = c < outW ? c : (outW - 1);   // clamped window base
    const float cmask = (c < outW) ? 1.f : 0.f;
    const int r0    = blockIdx.y * SH;
    const int riMax = min(r0 + SH + 9, H - 1);

    const float* pa = img1 + (((size_t)nc) << (2 * logH)) + cb;
    const float* pb = img2 + (((size_t)nc) << (2 * logH)) + cb;

    // fused downsample task (waves 0-1): one ds column pair per thread
    const int H2   = H >> 1;
    const int gdc  = blockIdx.x * 128 + tid;
    const int nc_d = gdc >> (logH - 1);
    const int cd   = gdc & (H2 - 1);
    const bool dth = do_ds && (tid < 128);
    const float* qa = img1 + (((size_t)nc_d) << (2 * logH)) + 2 * cd;
    const float* qb = img2 + (((size_t)nc_d) << (2 * logH)) + 2 * cd;
    float* o1 = ds1 + (size_t)nc_d * H2 * H2 + cd;
    float* o2 = ds2 + (size_t)nc_d * H2 * H2 + cd;
    v2f da = {0.f, 0.f}, db = {0.f, 0.f};

    float A[11][5];
    #pragma unroll
    for (int s = 0; s < 11; ++s)
        #pragma unroll
        for (int k = 0; k < 5; ++k) A[s][k] = 0.f;
    float ssim_t = 0.f, cs_t = 0.f;

#define STEP(U, CHK)                                                          \
    {                                                                         \
        const int m  = mb + (U);                                              \
        const int ri = r0 + m;                                                \
        if (!(CHK) || ri <= riMax) {                                          \
            const float* ra  = pa + (size_t)ri * H;                           \
            const float* rb_ = pb + (size_t)ri * H;                           \
            v4 A0 = *(const v4*)(ra);                                         \
            v4 A1 = *(const v4*)(ra + 4);                                     \
            v4 A2 = *(const v4*)(ra + 7);                                     \
            v4 B0 = *(const v4*)(rb_);                                        \
            v4 B1 = *(const v4*)(rb_ + 4);                                    \
            v4 B2 = *(const v4*)(rb_ + 7);                                    \
            float av[11] = {A0.x, A0.y, A0.z, A0.w, A1.x, A1.y, A1.z, A1.w,   \
                            A2.y, A2.z, A2.w};                                \
            float bv[11] = {B0.x, B0.y, B0.z, B0.w, B1.x, B1.y, B1.z, B1.w,   \
                            B2.y, B2.z, B2.w};                                \
            float hx = 0.f, hy = 0.f, hxx = 0.f, hyy = 0.f, hxy = 0.f;        \
            _Pragma("unroll")                                                 \
            for (int j = 0; j < 11; ++j) {                                    \
                float w = GW[j], a_ = av[j], b_ = bv[j];                      \
                float wa = w * a_, wb = w * b_;                               \
                hx += wa; hy += wb;                                           \
                hxx += wa * a_; hyy += wb * b_; hxy += wa * b_;               \
            }                                                                 \
            _Pragma("unroll")                                                 \
            for (int s = 0; s < 11; ++s) {                                    \
                const float w = GW[((U) - s + 11) % 11];                      \
                A[s][0] += w * hx;  A[s][1] += w * hy;                        \
                A[s][2] += w * hxx; A[s][3] += w * hyy; A[s][4] += w * hxy;   \
            }                                                                 \
            const int es = ((U) + 1) % 11;                                    \
            if (m >= 10) {                                                    \
                float mu1 = A[es][0], mu2 = A[es][1];                         \
                float m11 = mu1 * mu1, m22 = mu2 * mu2, m12 = mu1 * mu2;      \
                float sg1 = A[es][2] - m11, sg2 = A[es][3] - m22;             \
                float sg12 = A[es][4] - m12;                                  \
                float v1 = 2.f * sg12 + C2, vv2 = sg1 + sg2 + C2;             \
                float csv = v1 * frcp(vv2);                                   \
                float ssv = (2.f * m12 + C1) * csv * frcp(m11 + m22 + C1);    \
                cs_t   += cmask * csv;                                        \
                ssim_t += cmask * ssv;                                        \
            }                                                                 \
            A[es][0] = 0.f; A[es][1] = 0.f; A[es][2] = 0.f;                   \
            A[es][3] = 0.f; A[es][4] = 0.f;                                   \
            if (dth) {                                                        \
                v2f xa = *(const v2f*)(qa + (size_t)ri * H);                  \
                v2f xb = *(const v2f*)(qb + (size_t)ri * H);                  \
                if (ri & 1) {                                                 \
                    o1[(size_t)(ri >> 1) * H2] =                              \
                        0.25f * ((da.x + da.y) + (xa.x + xa.y));              \
                    o2[(size_t)(ri >> 1) * H2] =                              \
                        0.25f * ((db.x + db.y) + (xb.x + xb.y));              \
                } else { da = xa; db = xb; }                                  \
            }                                                                 \
        }                                                                     \
    }

    const int nsteps = riMax - r0 + 1;
    const int nmacro = (nsteps + 10) / 11;
    for (int macro = 0; macro < nmacro; ++macro) {
        const int mb = macro * 11;
        if (r0 + mb + 10 <= riMax) {
            // branch-free fast path: compiler can schedule loads ahead
            STEP(0, false) STEP(1, false) STEP(2, false) STEP(3, false)
            STEP(4, false) STEP(5, false) STEP(6, false) STEP(7, false)
            STEP(8, false) STEP(9, false) STEP(10, false)
        } else {
            STEP(0, true) STEP(1, true) STEP(2, true) STEP(3, true)
            STEP(4, true) STEP(5, true) STEP(6, true) STEP(7, true)
            STEP(8, true) STEP(9, true) STEP(10, true)
        }
    }
#undef STEP

    // ---- block reduction + spread atomics
    __shared__ float red[8];
    #pragma unroll
    for (int off = 32; off > 0; off >>= 1) {
        ssim_t += __shfl_down(ssim_t, off);
        cs_t   += __shfl_down(cs_t, off);
    }
    int wave = tid >> 6, lane = tid & 63;
    if (lane == 0) { red[wave] = ssim_t; red[4 + wave] = cs_t; }
    __syncthreads();
    if (tid == 0) {
        float s = red[0] + red[1] + red[2] + red[3];
        float c2 = red[4] + red[5] + red[6] + red[7];
        int slot = (blockIdx.x + blockIdx.y * 5) & (NSLOT - 1);
        atomicAdd(&acc[slot], s);
        atomicAdd(&acc[NSLOT + slot], c2);
    }
}

__global__ void finalize_kernel(const float* __restrict__ acc, float* __restrict__ out)
{
    if (threadIdx.x == 0 && blockIdx.x == 0) {
        const float w[5] = {0.0448f, 0.2856f, 0.3001f, 0.2363f, 0.1333f};
        float ms[5], mc[5];
        for (int l = 0; l < 5; ++l) {
            float s = 0.f, c = 0.f;
            for (int k = 0; k < NSLOT; ++k) {
                s += acc[2 * NSLOT * l + k];
                c += acc[2 * NSLOT * l + NSLOT + k];
            }
            int oh = (512 >> l) - 10;
            float cnt = 48.f * (float)oh * (float)oh;
            ms[l] = (s / cnt + 1.f) * 0.5f;
            mc[l] = (c / cnt + 1.f) * 0.5f;
        }
        float p2 = powf(ms[4], w[4]);
        float r = 1.f;
        for (int i = 0; i < 4; ++i) r *= powf(mc[i], w[i]) * p2;
        out[0] = r;
    }
}

extern "C" void kernel_launch(void* const* d_in, const int* in_sizes, int n_in,
                              void* d_out, int out_size, void* d_ws, size_t ws_size,
                              hipStream_t stream)
{
    const float* img1 = (const float*)d_in[0];
    const float* img2 = (const float*)d_in[1];
    float* out = (float*)d_out;
    float* ws  = (float*)d_ws;

    float* acc = ws;              // 5 levels x 2 x NSLOT floats
    size_t off = 512;

    const float* buf1[5];
    const float* buf2[5];
    float* wbuf1[5];
    float* wbuf2[5];
    buf1[0] = img1; buf2[0] = img2;
    for (int l = 1; l < 5; ++l) {
        int Hl = 512 >> l;
        size_t sz = (size_t)48 * Hl * Hl;
        wbuf1[l] = ws + off; off += sz;
        wbuf2[l] = ws + off; off += sz;
        buf1[l] = wbuf1[l];
        buf2[l] = wbuf2[l];
    }

    hipMemsetAsync(acc, 0, 5 * 2 * NSLOT * sizeof(float), stream);

    const int Hs[5]  = {512, 256, 128, 64, 32};
    const int lg[5]  = {9, 8, 7, 6, 5};
    const int SHs[5] = {64, 32, 16, 8, 8};

    for (int l = 0; l < 5; ++l) {
        int H = Hs[l];
        int outH = H - 10;
        int SH = SHs[l];
        int strips = (outH + SH - 1) / SH;
        int colb = 48 * H / 256;
        dim3 grid(colb, strips);
        ssim_roll_kernel<<<grid, 256, 0, stream>>>(
            buf1[l], buf2[l],
            l < 4 ? wbuf1[l + 1] : nullptr,
            l < 4 ? wbuf2[l + 1] : nullptr,
            H, lg[l], SH, l < 4 ? 1 : 0,
            acc + 2 * NSLOT * l);
    }

    finalize_kernel<<<1, 64, 0, stream>>>(acc, out);
}

// Round 4
// 249.024 us; speedup vs baseline: 1.7717x; 1.7717x over previous
//
#include <hip/hip_runtime.h>

// MS-SSIM, 5 levels, 16x3x512x512 fp32, scalar fp32 out.
//
// R4: tiled h-pass/v-pass with the s/d channel reduction.
//  s = x+y, d = x-y  ==> 4 h-filtered channels (S, D, SS, DD) instead of 5:
//    P = mu_s^2, Q = mu_d^2, U = E[s^2]-P, V = E[d^2]-Q
//    2*sig12+C2 = (U-V)/2+C2   sig1+sig2+C2 = (U+V)/2+C2
//    2*mu1mu2+C1 = (P-Q)/2+C1  mu1^2+mu2^2+C1 = (P+Q)/2+C1
//  LDS: per pixel-column float4 of the 4 channels, row pitch 33 v4
//  (conflict-free b128 reads, rows staggered 4 banks by the pad).
//  v-pass: 256 threads, thread = 1 column x TROWS/8 rows, rolling vertical
//  window: (TROWS/8 + 10) b128 reads per thread.
//  Downsample for the next level fused (block's core region tiles the image
//  exactly at every level). Tile height templated: 64/64/32/16/16 per level.

#define NSLOT 32

typedef float v4  __attribute__((ext_vector_type(4)));
typedef float v2f __attribute__((ext_vector_type(2)));

__device__ __forceinline__ float frcp(float x) { return __builtin_amdgcn_rcpf(x); }

template<int TROWS>
__global__ __launch_bounds__(256, 4) void ssim_tile_kernel(
    const float* __restrict__ img1, const float* __restrict__ img2,
    float* __restrict__ ds1, float* __restrict__ ds2,
    int H, int do_ds, float* __restrict__ acc)
{
    constexpr int HR    = TROWS + 10;   // h-rows per tile
    constexpr int OPT   = TROWS / 8;    // output rows per thread
    constexpr int PITCH = 33;           // v4 units per LDS row (32 + 1 pad)

    const float GW[11] = {0.00102840f, 0.00759877f, 0.03600070f, 0.10936069f,
                          0.21300636f, 0.26601172f, 0.21300636f, 0.10936069f,
                          0.03600070f, 0.00759877f, 0.00102840f};
    const float C1 = 1e-4f, C2 = 9e-4f;

    __shared__ v4 hb[HR * PITCH];
    __shared__ float red[8];

    const int tid  = threadIdx.x;
    const int nc   = blockIdx.z;
    const int tx0  = blockIdx.x * 32;
    const int ty0  = blockIdx.y * TROWS;
    const int outHW = H - 10;
    const float* p1 = img1 + (size_t)nc * H * H;
    const float* p2 = img2 + (size_t)nc * H * H;

    // ---- fused 2x2 avg-pool of this block's core region (independent work,
    //      overlaps the h-pass)
    if (do_ds) {
        const int H2 = H >> 1;
        const int cdd = tid & 15;
        #pragma unroll
        for (int r = tid >> 4; r < TROWS / 2; r += 16) {
            int iy = ty0 + 2 * r, ix = tx0 + 2 * cdd;
            if (iy + 1 < H) {
                v2f a0 = *(const v2f*)(p1 + (size_t)iy * H + ix);
                v2f a1 = *(const v2f*)(p1 + (size_t)(iy + 1) * H + ix);
                v2f b0 = *(const v2f*)(p2 + (size_t)iy * H + ix);
                v2f b1 = *(const v2f*)(p2 + (size_t)(iy + 1) * H + ix);
                size_t o = (size_t)nc * H2 * H2
                         + (size_t)((ty0 >> 1) + r) * H2 + ((tx0 >> 1) + cdd);
                ds1[o] = 0.25f * ((a0.x + a0.y) + (a1.x + a1.y));
                ds2[o] = 0.25f * ((b0.x + b0.y) + (b1.x + b1.y));
            }
        }
    }

    // ---- horizontal pass: HR rows x 8 col-groups (4 cols each)
    for (int task = tid; task < HR * 8; task += 256) {
        const int r  = task >> 3, cg = task & 7;
        const int gr = ty0 + r;
        const int c0 = tx0 + cg * 4;
        v4 hs = 0.f, hd = 0.f, hss = 0.f, hdd = 0.f;
        if (gr < H) {
            float s[16], d[16];
            if (c0 + 16 <= H) {
                const float* pa = p1 + (size_t)gr * H + c0;
                const float* pb = p2 + (size_t)gr * H + c0;
                #pragma unroll
                for (int q = 0; q < 4; ++q) {
                    v4 va = *(const v4*)(pa + 4 * q);
                    v4 vb = *(const v4*)(pb + 4 * q);
                    v4 sv = va + vb, dv = va - vb;
                    s[4*q+0] = sv.x; s[4*q+1] = sv.y; s[4*q+2] = sv.z; s[4*q+3] = sv.w;
                    d[4*q+0] = dv.x; d[4*q+1] = dv.y; d[4*q+2] = dv.z; d[4*q+3] = dv.w;
                }
            } else {
                #pragma unroll
                for (int q = 0; q < 16; ++q) {
                    int cc = c0 + q;
                    float a = (cc < H) ? p1[(size_t)gr * H + cc] : 0.f;
                    float b = (cc < H) ? p2[(size_t)gr * H + cc] : 0.f;
                    s[q] = a + b; d[q] = a - b;
                }
            }
            #pragma unroll
            for (int j = 0; j < 11; ++j) {
                float w = GW[j];
                v4 sv = {s[j], s[j+1], s[j+2], s[j+3]};
                v4 dv = {d[j], d[j+1], d[j+2], d[j+3]};
                v4 ws = w * sv, wd = w * dv;
                hs += ws; hd += wd; hss += ws * sv; hdd += wd * dv;
            }
        }
        v4* row = &hb[r * PITCH + cg * 4];
        row[0] = (v4){hs.x, hd.x, hss.x, hdd.x};
        row[1] = (v4){hs.y, hd.y, hss.y, hdd.y};
        row[2] = (v4){hs.z, hd.z, hss.z, hdd.z};
        row[3] = (v4){hs.w, hd.w, hss.w, hdd.w};
    }
    __syncthreads();

    // ---- vertical pass + ssim/cs: thread = 1 column x OPT rows (rolling)
    const int col  = tid & 31;
    const int row0 = (tid >> 5) * OPT;
    const float colm = (tx0 + col < outHW) ? 1.f : 0.f;
    v4 A[OPT];
    #pragma unroll
    for (int k = 0; k < OPT; ++k) A[k] = 0.f;

    #pragma unroll
    for (int r = 0; r < OPT + 10; ++r) {
        v4 h = hb[(row0 + r) * PITCH + col];
        #pragma unroll
        for (int k = 0; k < OPT; ++k) {
            constexpr int dummy = 0; (void)dummy;
            const int j = r - k;
            if (j >= 0 && j < 11) A[k] += GW[j] * h;
        }
    }

    float ssim_t = 0.f, cs_t = 0.f;
    #pragma unroll
    for (int k = 0; k < OPT; ++k) {
        float mask = colm * ((ty0 + row0 + k < outHW) ? 1.f : 0.f);
        float mu_s = A[k].x, mu_d = A[k].y;
        float P = mu_s * mu_s, Q = mu_d * mu_d;
        float U = A[k].z - P, V = A[k].w - Q;
        float v1 = 0.5f * (U - V) + C2;
        float v2 = 0.5f * (U + V) + C2;
        float n1 = 0.5f * (P - Q) + C1;
        float d1 = 0.5f * (P + Q) + C1;
        float csv = v1 * frcp(v2);
        float ssv = n1 * csv * frcp(d1);
        cs_t   += mask * csv;
        ssim_t += mask * ssv;
    }

    // ---- block reduction + spread atomics
    #pragma unroll
    for (int off = 32; off > 0; off >>= 1) {
        ssim_t += __shfl_down(ssim_t, off);
        cs_t   += __shfl_down(cs_t, off);
    }
    int wave = tid >> 6, lane = tid & 63;
    if (lane == 0) { red[wave] = ssim_t; red[4 + wave] = cs_t; }
    __syncthreads();
    if (tid == 0) {
        float s = red[0] + red[1] + red[2] + red[3];
        float c2s = red[4] + red[5] + red[6] + red[7];
        int slot = (blockIdx.x + blockIdx.y * 5 + blockIdx.z * 11) & (NSLOT - 1);
        atomicAdd(&acc[slot], s);
        atomicAdd(&acc[NSLOT + slot], c2s);
    }
}

__global__ void finalize_kernel(const float* __restrict__ acc, float* __restrict__ out)
{
    if (threadIdx.x == 0 && blockIdx.x == 0) {
        const float w[5] = {0.0448f, 0.2856f, 0.3001f, 0.2363f, 0.1333f};
        float ms[5], mc[5];
        for (int l = 0; l < 5; ++l) {
            float s = 0.f, c = 0.f;
            for (int k = 0; k < NSLOT; ++k) {
                s += acc[2 * NSLOT * l + k];
                c += acc[2 * NSLOT * l + NSLOT + k];
            }
            int oh = (512 >> l) - 10;
            float cnt = 48.f * (float)oh * (float)oh;
            ms[l] = (s / cnt + 1.f) * 0.5f;
            mc[l] = (c / cnt + 1.f) * 0.5f;
        }
        float p2 = powf(ms[4], w[4]);
        float r = 1.f;
        for (int i = 0; i < 4; ++i) r *= powf(mc[i], w[i]) * p2;
        out[0] = r;
    }
}

extern "C" void kernel_launch(void* const* d_in, const int* in_sizes, int n_in,
                              void* d_out, int out_size, void* d_ws, size_t ws_size,
                              hipStream_t stream)
{
    const float* img1 = (const float*)d_in[0];
    const float* img2 = (const float*)d_in[1];
    float* out = (float*)d_out;
    float* ws  = (float*)d_ws;

    float* acc = ws;              // 5 levels x 2 x NSLOT floats
    size_t off = 512;

    const float* buf1[5];
    const float* buf2[5];
    float* wbuf1[5];
    float* wbuf2[5];
    buf1[0] = img1; buf2[0] = img2;
    for (int l = 1; l < 5; ++l) {
        int Hl = 512 >> l;
        size_t sz = (size_t)48 * Hl * Hl;
        wbuf1[l] = ws + off; off += sz;
        wbuf2[l] = ws + off; off += sz;
        buf1[l] = wbuf1[l];
        buf2[l] = wbuf2[l];
    }

    hipMemsetAsync(acc, 0, 5 * 2 * NSLOT * sizeof(float), stream);

    const int Hs[5] = {512, 256, 128, 64, 32};
    const int Ts[5] = {64, 64, 32, 16, 16};

    for (int l = 0; l < 5; ++l) {
        int H = Hs[l], T = Ts[l];
        int outH = H - 10;
        int ctiles = (outH + 31) / 32;
        int rtiles = (outH + T - 1) / T;
        dim3 grid(ctiles, rtiles, 48);
        float* d1 = l < 4 ? wbuf1[l + 1] : nullptr;
        float* d2 = l < 4 ? wbuf2[l + 1] : nullptr;
        int dd = l < 4 ? 1 : 0;
        float* a = acc + 2 * NSLOT * l;
        if (T == 64)
            ssim_tile_kernel<64><<<grid, 256, 0, stream>>>(buf1[l], buf2[l], d1, d2, H, dd, a);
        else if (T == 32)
            ssim_tile_kernel<32><<<grid, 256, 0, stream>>>(buf1[l], buf2[l], d1, d2, H, dd, a);
        else
            ssim_tile_kernel<16><<<grid, 256, 0, stream>>>(buf1[l], buf2[l], d1, d2, H, dd, a);
    }

    finalize_kernel<<<1, 64, 0, stream>>>(acc, out);
}

// Round 5
// 242.727 us; speedup vs baseline: 1.8177x; 1.0259x over previous
//
#include <hip/hip_runtime.h>

// MS-SSIM, 5 levels, 16x3x512x512 fp32, scalar fp32 out.
//
// R5: R4's tiled h/v-pass (s/d channel reduction, per-column float4 LDS,
// pitch 33) with the occupancy ceiling raised: T=64 tile now runs 512-thread
// blocks under __launch_bounds__(512,8) -> 4 blocks/CU x 8 waves = 32
// waves/CU (100%) at the same 39KB LDS. Small levels use T=32/256thr
// (22KB, 7 blocks/CU) and T=16/256thr.
//  s = x+y, d = x-y  ==> 4 h-channels (S, D, SS, DD):
//    2*sig12+C2 = (U-V)/2+C2   sig1+sig2+C2 = (U+V)/2+C2
//    2*mu1mu2+C1 = (P-Q)/2+C1  mu1^2+mu2^2+C1 = (P+Q)/2+C1
//  Downsample for the next level fused into each block's core region.

#define NSLOT 32

typedef float v4  __attribute__((ext_vector_type(4)));
typedef float v2f __attribute__((ext_vector_type(2)));

__device__ __forceinline__ float frcp(float x) { return __builtin_amdgcn_rcpf(x); }

template<int TROWS, int NTHR, int MINW>
__global__ __launch_bounds__(NTHR, MINW) void ssim_tile_kernel(
    const float* __restrict__ img1, const float* __restrict__ img2,
    float* __restrict__ ds1, float* __restrict__ ds2,
    int H, int do_ds, float* __restrict__ acc)
{
    constexpr int HR    = TROWS + 10;          // h-rows per tile
    constexpr int OPT   = TROWS * 32 / NTHR;   // output rows per thread
    constexpr int PITCH = 33;                  // v4 units per LDS row
    constexpr int NW    = NTHR / 64;           // waves per block

    const float GW[11] = {0.00102840f, 0.00759877f, 0.03600070f, 0.10936069f,
                          0.21300636f, 0.26601172f, 0.21300636f, 0.10936069f,
                          0.03600070f, 0.00759877f, 0.00102840f};
    const float C1 = 1e-4f, C2 = 9e-4f;

    __shared__ v4 hb[HR * PITCH];
    __shared__ float red[2 * NW];

    const int tid  = threadIdx.x;
    const int nc   = blockIdx.z;
    const int tx0  = blockIdx.x * 32;
    const int ty0  = blockIdx.y * TROWS;
    const int outHW = H - 10;
    const float* p1 = img1 + (size_t)nc * H * H;
    const float* p2 = img2 + (size_t)nc * H * H;

    // ---- fused 2x2 avg-pool of the block's core region (independent work)
    if (do_ds) {
        const int H2 = H >> 1;
        #pragma unroll
        for (int t = tid; t < 16 * (TROWS / 2); t += NTHR) {
            int r = t >> 4, cdd = t & 15;
            int iy = ty0 + 2 * r, ix = tx0 + 2 * cdd;
            if (iy + 1 < H) {
                v2f a0 = *(const v2f*)(p1 + (size_t)iy * H + ix);
                v2f a1 = *(const v2f*)(p1 + (size_t)(iy + 1) * H + ix);
                v2f b0 = *(const v2f*)(p2 + (size_t)iy * H + ix);
                v2f b1 = *(const v2f*)(p2 + (size_t)(iy + 1) * H + ix);
                size_t o = (size_t)nc * H2 * H2
                         + (size_t)((ty0 >> 1) + r) * H2 + ((tx0 >> 1) + cdd);
                ds1[o] = 0.25f * ((a0.x + a0.y) + (a1.x + a1.y));
                ds2[o] = 0.25f * ((b0.x + b0.y) + (b1.x + b1.y));
            }
        }
    }

    // ---- horizontal pass: HR rows x 8 col-groups (4 cols each)
    for (int task = tid; task < HR * 8; task += NTHR) {
        const int r  = task >> 3, cg = task & 7;
        const int gr = ty0 + r;
        const int c0 = tx0 + cg * 4;
        v4 hs = 0.f, hd = 0.f, hss = 0.f, hdd = 0.f;
        if (gr < H) {
            float s[16], d[16];
            if (c0 + 16 <= H) {
                const float* pa = p1 + (size_t)gr * H + c0;
                const float* pb = p2 + (size_t)gr * H + c0;
                #pragma unroll
                for (int q = 0; q < 4; ++q) {
                    v4 va = *(const v4*)(pa + 4 * q);
                    v4 vb = *(const v4*)(pb + 4 * q);
                    v4 sv = va + vb, dv = va - vb;
                    s[4*q+0] = sv.x; s[4*q+1] = sv.y; s[4*q+2] = sv.z; s[4*q+3] = sv.w;
                    d[4*q+0] = dv.x; d[4*q+1] = dv.y; d[4*q+2] = dv.z; d[4*q+3] = dv.w;
                }
            } else {
                #pragma unroll
                for (int q = 0; q < 16; ++q) {
                    int cc = c0 + q;
                    float a = (cc < H) ? p1[(size_t)gr * H + cc] : 0.f;
                    float b = (cc < H) ? p2[(size_t)gr * H + cc] : 0.f;
                    s[q] = a + b; d[q] = a - b;
                }
            }
            #pragma unroll
            for (int j = 0; j < 11; ++j) {
                float w = GW[j];
                v4 sv = {s[j], s[j+1], s[j+2], s[j+3]};
                v4 dv = {d[j], d[j+1], d[j+2], d[j+3]};
                v4 ws = w * sv, wd = w * dv;
                hs += ws; hd += wd; hss += ws * sv; hdd += wd * dv;
            }
        }
        v4* row = &hb[r * PITCH + cg * 4];
        row[0] = (v4){hs.x, hd.x, hss.x, hdd.x};
        row[1] = (v4){hs.y, hd.y, hss.y, hdd.y};
        row[2] = (v4){hs.z, hd.z, hss.z, hdd.z};
        row[3] = (v4){hs.w, hd.w, hss.w, hdd.w};
    }
    __syncthreads();

    // ---- vertical pass + ssim/cs: thread = 1 column x OPT rows (rolling)
    const int col  = tid & 31;
    const int row0 = (tid >> 5) * OPT;
    const float colm = (tx0 + col < outHW) ? 1.f : 0.f;
    v4 A[OPT];
    #pragma unroll
    for (int k = 0; k < OPT; ++k) A[k] = 0.f;

    #pragma unroll
    for (int r = 0; r < OPT + 10; ++r) {
        v4 h = hb[(row0 + r) * PITCH + col];
        #pragma unroll
        for (int k = 0; k < OPT; ++k) {
            const int j = r - k;
            if (j >= 0 && j < 11) A[k] += GW[j] * h;
        }
    }

    float ssim_t = 0.f, cs_t = 0.f;
    #pragma unroll
    for (int k = 0; k < OPT; ++k) {
        float mask = colm * ((ty0 + row0 + k < outHW) ? 1.f : 0.f);
        float mu_s = A[k].x, mu_d = A[k].y;
        float P = mu_s * mu_s, Q = mu_d * mu_d;
        float U = A[k].z - P, V = A[k].w - Q;
        float v1 = 0.5f * (U - V) + C2;
        float v2 = 0.5f * (U + V) + C2;
        float n1 = 0.5f * (P - Q) + C1;
        float d1 = 0.5f * (P + Q) + C1;
        float csv = v1 * frcp(v2);
        float ssv = n1 * csv * frcp(d1);
        cs_t   += mask * csv;
        ssim_t += mask * ssv;
    }

    // ---- block reduction + spread atomics
    #pragma unroll
    for (int off = 32; off > 0; off >>= 1) {
        ssim_t += __shfl_down(ssim_t, off);
        cs_t   += __shfl_down(cs_t, off);
    }
    int wave = tid >> 6, lane = tid & 63;
    if (lane == 0) { red[wave] = ssim_t; red[NW + wave] = cs_t; }
    __syncthreads();
    if (tid == 0) {
        float s = 0.f, c2s = 0.f;
        #pragma unroll
        for (int w = 0; w < NW; ++w) { s += red[w]; c2s += red[NW + w]; }
        int slot = (blockIdx.x + blockIdx.y * 5 + blockIdx.z * 11) & (NSLOT - 1);
        atomicAdd(&acc[slot], s);
        atomicAdd(&acc[NSLOT + slot], c2s);
    }
}

__global__ void finalize_kernel(const float* __restrict__ acc, float* __restrict__ out)
{
    if (threadIdx.x == 0 && blockIdx.x == 0) {
        const float w[5] = {0.0448f, 0.2856f, 0.3001f, 0.2363f, 0.1333f};
        float ms[5], mc[5];
        for (int l = 0; l < 5; ++l) {
            float s = 0.f, c = 0.f;
            for (int k = 0; k < NSLOT; ++k) {
                s += acc[2 * NSLOT * l + k];
                c += acc[2 * NSLOT * l + NSLOT + k];
            }
            int oh = (512 >> l) - 10;
            float cnt = 48.f * (float)oh * (float)oh;
            ms[l] = (s / cnt + 1.f) * 0.5f;
            mc[l] = (c / cnt + 1.f) * 0.5f;
        }
        float p2 = powf(ms[4], w[4]);
        float r = 1.f;
        for (int i = 0; i < 4; ++i) r *= powf(mc[i], w[i]) * p2;
        out[0] = r;
    }
}

extern "C" void kernel_launch(void* const* d_in, const int* in_sizes, int n_in,
                              void* d_out, int out_size, void* d_ws, size_t ws_size,
                              hipStream_t stream)
{
    const float* img1 = (const float*)d_in[0];
    const float* img2 = (const float*)d_in[1];
    float* out = (float*)d_out;
    float* ws  = (float*)d_ws;

    float* acc = ws;              // 5 levels x 2 x NSLOT floats
    size_t off = 512;

    const float* buf1[5];
    const float* buf2[5];
    float* wbuf1[5];
    float* wbuf2[5];
    buf1[0] = img1; buf2[0] = img2;
    for (int l = 1; l < 5; ++l) {
        int Hl = 512 >> l;
        size_t sz = (size_t)48 * Hl * Hl;
        wbuf1[l] = ws + off; off += sz;
        wbuf2[l] = ws + off; off += sz;
        buf1[l] = wbuf1[l];
        buf2[l] = wbuf2[l];
    }

    hipMemsetAsync(acc, 0, 5 * 2 * NSLOT * sizeof(float), stream);

    const int Hs[5] = {512, 256, 128, 64, 32};
    const int Ts[5] = {64, 64, 32, 16, 16};

    for (int l = 0; l < 5; ++l) {
        int H = Hs[l], T = Ts[l];
        int outH = H - 10;
        int ctiles = (outH + 31) / 32;
        int rtiles = (outH + T - 1) / T;
        dim3 grid(ctiles, rtiles, 48);
        float* d1 = l < 4 ? wbuf1[l + 1] : nullptr;
        float* d2 = l < 4 ? wbuf2[l + 1] : nullptr;
        int dd = l < 4 ? 1 : 0;
        float* a = acc + 2 * NSLOT * l;
        if (T == 64)
            ssim_tile_kernel<64, 512, 8><<<grid, 512, 0, stream>>>(buf1[l], buf2[l], d1, d2, H, dd, a);
        else if (T == 32)
            ssim_tile_kernel<32, 256, 7><<<grid, 256, 0, stream>>>(buf1[l], buf2[l], d1, d2, H, dd, a);
        else
            ssim_tile_kernel<16, 256, 8><<<grid, 256, 0, stream>>>(buf1[l], buf2[l], d1, d2, H, dd, a);
    }

    finalize_kernel<<<1, 64, 0, stream>>>(acc, out);
}